// Round 9
// baseline (174.333 us; speedup 1.0000x reference)
//
#include <hip/hip_runtime.h>
#include <hip/hip_bf16.h>
#include <hip/hip_fp8.h>
#include <math.h>

typedef float f32x4 __attribute__((ext_vector_type(4)));
typedef int   i32x4 __attribute__((ext_vector_type(4)));
typedef int   v8i   __attribute__((ext_vector_type(8)));

constexpr int Nn = 8192;   // B*S
constexpr int Dd = 256;    // feature dim (== bytes per fp8 row)
constexpr float LOG2E     = 1.4426950408889634f;
constexpr float SIM_SCALE = 20.0f * LOG2E;   // (1/tau)*log2(e), tau=0.05
constexpr float SIM_BIAS  = -20.0f * LOG2E;  // fixed max = 1/tau (|q.k|<=1)
constexpr int   SCALE1    = 0x7F7F7F7F;      // E8M0 127 = 2^0 in every byte
constexpr int   BCAP      = 512;             // bucket capacity (mean ~8)

// async global->LDS DMA, 16B/lane; LDS dst = wave-uniform base + lane*16.
typedef __attribute__((address_space(1))) const unsigned int gu32;
typedef __attribute__((address_space(3))) unsigned int lu32;
__device__ __forceinline__ void gload16(const unsigned char* g, unsigned char* l) {
  __builtin_amdgcn_global_load_lds((gu32*)(uintptr_t)g, (lu32*)(uintptr_t)l, 16, 0, 0);
}

#define VMCNT4() asm volatile("s_waitcnt vmcnt(4)" ::: "memory")
#define VMCNT0() asm volatile("s_waitcnt vmcnt(0)" ::: "memory")
#define LGKM0()  asm volatile("s_waitcnt lgkmcnt(0)" ::: "memory")
#define SCHEDB() __builtin_amdgcn_sched_barrier(0)
#define BAR()    __builtin_amdgcn_s_barrier()

__device__ __forceinline__ float fp8f(unsigned int b) {
  __hip_fp8_e4m3 v; v.__x = (unsigned char)(b & 0xffu); return (float)v;
}

// ---------------------------------------------------------------------------
// Kernel 1: L2-normalize rows -> fp8 e4m3; init cbias (SIM_BIAS pre-folded),
// g_all, bucket counts, loss accumulators.
// ---------------------------------------------------------------------------
__global__ __launch_bounds__(256) void prep_kernel(const float* __restrict__ logits,
                                                   const float* __restrict__ labels,
                                                   const int* __restrict__ pad,
                                                   unsigned char* __restrict__ qb,
                                                   unsigned char* __restrict__ kb,
                                                   float* __restrict__ cbias,
                                                   float* __restrict__ g_all,
                                                   int* __restrict__ cnt,
                                                   float* __restrict__ accS,
                                                   float* __restrict__ accC,
                                                   int* __restrict__ done) {
  const int j = blockIdx.x * 256 + threadIdx.x;
  if (j < Nn) {
    cbias[j] = pad[j] ? SIM_BIAS : -1e30f;   // SIM_BIAS folded in (col term)
    g_all[j] = 0.0f;
  }
  if (j < BCAP) cnt[j] = 0;
  if (j == 0) { *accS = 0.f; *accC = 0.f; *done = 0; }

  const int gw   = (blockIdx.x * 256 + threadIdx.x) >> 6;
  const int lane = threadIdx.x & 63;
  const float* src;
  unsigned char* dst;
  int row;
  if (gw < Nn) { src = logits; dst = qb; row = gw; }
  else         { src = labels; dst = kb; row = gw - Nn; }

  const float4 v = *reinterpret_cast<const float4*>(src + (size_t)row * Dd + lane * 4);
  float ss = v.x * v.x + v.y * v.y + v.z * v.z + v.w * v.w;
#pragma unroll
  for (int m = 32; m >= 1; m >>= 1) ss += __shfl_xor(ss, m);
  const float scale = 1.0f / fmaxf(sqrtf(ss), 1e-12f);

  const __hip_fp8_e4m3 e0(v.x * scale);
  const __hip_fp8_e4m3 e1(v.y * scale);
  const __hip_fp8_e4m3 e2(v.z * scale);
  const __hip_fp8_e4m3 e3(v.w * scale);
  const unsigned int packed = (unsigned int)e0.__x |
                              ((unsigned int)e1.__x << 8) |
                              ((unsigned int)e2.__x << 16) |
                              ((unsigned int)e3.__x << 24);
  reinterpret_cast<unsigned int*>(dst + (size_t)row * Dd)[lane] = packed;
}

// ---------------------------------------------------------------------------
// Kernel 2 (R22): R19's verified skeleton (LDS 3-slot B ring, counted vmcnt,
// A-hoist, atomics-at-retire) with ALL pos logic REMOVED from the epilogue:
//   per element = fmaf + exp2 + add  (was fmaf+exp2+cmp+cndmask+2 add).
//   rowAd/colAd metadata gone -> meta = 4 loads/tile (vmcnt ring re-derived:
//   even-top in flight = Eprev(4)+Oprev(4) -> VMCNT4 drains tile 2ct;
//   odd-top = Oprev(4)+meta(4)+Ecur(4) -> VMCNT4 drains tile 2ct+1 ✓).
// Additionally, blockIdx.y==0 blocks fill the per-ad column buckets (read
// only by kernel 3, i.e. strictly after this kernel -> no ordering hazard).
// ---------------------------------------------------------------------------
__global__ __launch_bounds__(256, 2) void gemm_lse_kernel(const unsigned char* __restrict__ qb,
                                                          const unsigned char* __restrict__ kb,
                                                          const float* __restrict__ cbias,
                                                          const int* __restrict__ ad,
                                                          const int* __restrict__ pad,
                                                          float* __restrict__ g_all,
                                                          int* __restrict__ cnt,
                                                          int* __restrict__ lists) {
  __shared__ unsigned char smem[49152];
  // prologue: A.k0 [0,16K), A.k1 [16K,32K), B slot0 [32K,48K)
  // loop: B ring slot0=[32K,48K) slot1=[0,16K) slot2=[16K,32K), tile t -> t%3

  const int tid  = threadIdx.x;

  // ---- bucket fill (64 blocks x 256 thr >= 8192; readers run next kernel) --
  if (blockIdx.y == 0) {
    const int t = blockIdx.x * 256 + tid;
    if (t < Nn && pad[t]) {
      const int a = ad[t];
      const int slot = atomicAdd(&cnt[a], 1);
      if (slot < BCAP) lists[a * BCAP + slot] = t;
    }
  }

  const int lane = tid & 63;
  const int w    = tid >> 6;        // 0..3
  const int wrow  = (w >> 1) * 64;  // 0 or 64
  const int wcolL = (w & 1) * 64;   // 0 or 64 within the 128-col tile
  const int lq   = lane & 15;
  const int qd   = lane >> 4;
  const int rowBase = blockIdx.x * 128;
  const int colBase = blockIdx.y * 1024;   // 8 col-tiles of 128

  // staging constants (verified): wave w, iter i fills 8 LDS rows;
  // lane l -> row +(l>>3), logical 16B group (l&7)^(l>>3) (linear LDS dst).
  const int srl = lane >> 3;
  const int cg  = (lane & 7) ^ srl;
  const unsigned char* gA0 = qb + (size_t)(rowBase + w * 32 + srl) * Dd + cg * 16;
  const unsigned char* gB0 = kb + (size_t)(colBase + w * 32 + srl) * Dd + cg * 16;

  // ---- prologue: stage A (both K-halves) then B tile0 -> slot0 ----
#pragma unroll
  for (int kk = 0; kk < 2; ++kk)
#pragma unroll
    for (int i = 0; i < 4; ++i)
      gload16(gA0 + (size_t)i * 8 * Dd + kk * 128,
              &smem[kk * 16384 + (w * 32 + i * 8) * 128]);
#pragma unroll
  for (int i = 0; i < 4; ++i)
    gload16(gB0 + (size_t)i * 8 * Dd, &smem[32768 + (w * 32 + i * 8) * 128]);

  float apA[4][4];
#pragma unroll
  for (int mt = 0; mt < 4; ++mt)
#pragma unroll
    for (int r = 0; r < 4; ++r)
      apA[mt][r] = 0.f;

  VMCNT4();   // A's 8 loads (oldest) complete; tile0's 4 may remain
  BAR();

  // ---- one-time A fragment hoist (A LDS region dead afterwards) ----
  const int sl = lq & 7;                  // == r&7 for every fragment row
  const int s0 = ((qd * 2) ^ sl) << 4;
  const int s1 = ((qd * 2 + 1) ^ sl) << 4;

  v8i afReg[2][4];
#pragma unroll
  for (int kk = 0; kk < 2; ++kk) {
    const unsigned char* Ah = &smem[kk * 16384];
#pragma unroll
    for (int mt = 0; mt < 4; ++mt) {
      const int rb = (wrow + mt * 16 + lq) * 128;
      i32x4* ph_ = reinterpret_cast<i32x4*>(&afReg[kk][mt]);
      ph_[0] = *reinterpret_cast<const i32x4*>(&Ah[rb + s0]);
      ph_[1] = *reinterpret_cast<const i32x4*>(&Ah[rb + s1]);
    }
  }

  __syncthreads();  // full drain (once): hoist reads done in ALL waves before
                    // slots 1/2 overwrite the A region; tile0 DMA also done.

  {  // issue tile1 -> slot1 [0,16K)
    unsigned char* dB = &smem[0 + (w * 32) * 128];
    const unsigned char* g = gB0 + 128;  // ct=0, kk=1
#pragma unroll
    for (int i = 0; i < 4; ++i)
      gload16(g + (size_t)i * 8 * Dd, dB + i * 8 * 128);
  }

  const f32x4 CZ = (f32x4){0.f, 0.f, 0.f, 0.f};
  f32x4 c[4][4];
  float colB[4];

  for (int ct = 0; ct < 8; ++ct) {
    // slot bases for tiles 2ct, 2ct+1, 2ct+2, 2ct+3 (ring: tile t -> t%3)
    const int sA = (2 * ct) % 3;
    const unsigned bas0 = (sA == 0) ? 32768u : ((sA == 1) ? 0u : 16384u);
    const unsigned bas1 = (sA == 2) ? 32768u : ((sA == 0) ? 0u : 16384u);   // (2ct+1)%3
    const unsigned bas2 = (sA == 1) ? 32768u : ((sA == 2) ? 0u : 16384u);   // (2ct+2)%3
    const unsigned bas3 = bas0;                                             // (2ct+3)%3

    // ================= t = 2ct (kk=0): C-in = 0 =================
    {
      VMCNT4();   // tile 2ct (issued 2 barriers ago) complete; 2ct+1 in flight
      BAR();

      // col metadata first (so its vmcnt slot retires before the stage's)
#pragma unroll
      for (int nt = 0; nt < 4; ++nt)
        colB[nt] = cbias[colBase + ct * 128 + wcolL + nt * 16 + lq];

      if (ct < 7) {  // issue tile 2ct+2 -> bas2 (its old readers are done)
        unsigned char* dB = &smem[bas2 + (w * 32) * 128];
        const unsigned char* g = gB0 + (size_t)((ct + 1) * 128) * Dd;
#pragma unroll
        for (int i = 0; i < 4; ++i)
          gload16(g + (size_t)i * 8 * Dd, dB + i * 8 * 128);
      }

      const unsigned char* Bh = &smem[bas0];
#pragma unroll
      for (int nt = 0; nt < 4; ++nt) {
        const int rb = (wcolL + nt * 16 + lq) * 128;
        v8i bf;
        i32x4* pb = reinterpret_cast<i32x4*>(&bf);
        pb[0] = *reinterpret_cast<const i32x4*>(&Bh[rb + s0]);
        pb[1] = *reinterpret_cast<const i32x4*>(&Bh[rb + s1]);
#pragma unroll
        for (int mt = 0; mt < 4; ++mt)
          c[mt][nt] = __builtin_amdgcn_mfma_scale_f32_16x16x128_f8f6f4(
              afReg[0][mt], bf, CZ, 0, 0, 0, SCALE1, 0, SCALE1);
      }
      LGKM0();   // pin this phase's ds_reads inside the phase (rule #18)
      SCHEDB();
    }

    // ================= t = 2ct+1 (kk=1): accumulate + epilogue =================
    {
      if (ct < 7) { VMCNT4(); } else { VMCNT0(); }  // tile 2ct+1 complete
      BAR();

      if (ct < 7) {  // issue tile 2ct+3 -> bas3
        unsigned char* dB = &smem[bas3 + (w * 32) * 128];
        const unsigned char* g = gB0 + (size_t)((ct + 1) * 128) * Dd + 128;
#pragma unroll
        for (int i = 0; i < 4; ++i)
          gload16(g + (size_t)i * 8 * Dd, dB + i * 8 * 128);
      }

      const unsigned char* Bh = &smem[bas1];
#pragma unroll
      for (int nt = 0; nt < 4; ++nt) {
        const int rb = (wcolL + nt * 16 + lq) * 128;
        v8i bf;
        i32x4* pb = reinterpret_cast<i32x4*>(&bf);
        pb[0] = *reinterpret_cast<const i32x4*>(&Bh[rb + s0]);
        pb[1] = *reinterpret_cast<const i32x4*>(&Bh[rb + s1]);
#pragma unroll
        for (int mt = 0; mt < 4; ++mt)
          c[mt][nt] = __builtin_amdgcn_mfma_scale_f32_16x16x128_f8f6f4(
              afReg[1][mt], bf, c[mt][nt], 0, 0, 0, SCALE1, 0, SCALE1);
      }
      LGKM0();
      SCHEDB();

      // ---- epilogue: all-sum only (fmaf + exp2 + add per element) ----
#pragma unroll
      for (int mt = 0; mt < 4; ++mt) {
#pragma unroll
        for (int r = 0; r < 4; ++r) {
          float a = 0.f;
#pragma unroll
          for (int nt = 0; nt < 4; ++nt)
            a += __builtin_amdgcn_exp2f(fmaf(c[mt][nt][r], SIM_SCALE, colB[nt]));
          apA[mt][r] += a;
        }
      }
    }
  }

  // ---- final reduction: shfl-tree over the 16 lq lanes, then one atomic ----
#pragma unroll
  for (int mt = 0; mt < 4; ++mt) {
#pragma unroll
    for (int r = 0; r < 4; ++r) {
      float a = apA[mt][r];
#pragma unroll
      for (int m = 1; m < 16; m <<= 1)
        a += __shfl_xor(a, m);
      if (lq == 0) {
        const int row = rowBase + wrow + mt * 16 + qd * 4 + r;
        atomicAdd(&g_all[row], a);
      }
    }
  }
}

// ---------------------------------------------------------------------------
// Kernel 3 (R22): sparse pos-sum + loss finalize.  One wave per row:
// p_i = sum over bucket[ad_i] of exp2(q_i.k_j * SIM_SCALE + SIM_BIAS)
// (fp8-dequant dot, 2-deep prefetch; ~8 cols/row avg, TLP hides L2 latency).
// Row term = log(g_all) - log(p); block partials -> device atomics; the
// last block (done counter) finalizes out = S / max(C,1) via atomic reads.
// ---------------------------------------------------------------------------
__global__ __launch_bounds__(256) void pos_loss_kernel(const unsigned char* __restrict__ qb,
                                                       const unsigned char* __restrict__ kb,
                                                       const float* __restrict__ g_all,
                                                       const int* __restrict__ pad,
                                                       const int* __restrict__ ad,
                                                       const int* __restrict__ cnt,
                                                       const int* __restrict__ lists,
                                                       float* __restrict__ accS,
                                                       float* __restrict__ accC,
                                                       int* __restrict__ done,
                                                       float* __restrict__ out,
                                                       int nblocks) {
  const int tid  = threadIdx.x;
  const int lane = tid & 63;
  const int w    = tid >> 6;
  const int row  = blockIdx.x * 4 + w;

  float sTerm = 0.f, cTerm = 0.f;
  if (pad[row]) {
    const unsigned int qw =
        reinterpret_cast<const unsigned int*>(qb + (size_t)row * Dd)[lane];
    const float q0 = fp8f(qw), q1 = fp8f(qw >> 8),
                q2 = fp8f(qw >> 16), q3 = fp8f(qw >> 24);
    const int a = ad[row];
    int m = cnt[a];
    if (m > BCAP) m = BCAP;          // impossible for this input; safety
    const int* lst = lists + a * BCAP;

    float p = 0.f;
    // 2-deep prefetch over the bucket (m >= 1: row itself is in its bucket)
    unsigned int kw =
        reinterpret_cast<const unsigned int*>(kb + (size_t)lst[0] * Dd)[lane];
    for (int s = 0; s < m; ++s) {
      const unsigned int kwc = kw;
      if (s + 1 < m)
        kw = reinterpret_cast<const unsigned int*>(kb + (size_t)lst[s + 1] * Dd)[lane];
      float d = q0 * fp8f(kwc);
      d = fmaf(q1, fp8f(kwc >> 8), d);
      d = fmaf(q2, fp8f(kwc >> 16), d);
      d = fmaf(q3, fp8f(kwc >> 24), d);
#pragma unroll
      for (int mm = 32; mm >= 1; mm >>= 1) d += __shfl_xor(d, mm);
      p += __builtin_amdgcn_exp2f(fmaf(d, SIM_SCALE, SIM_BIAS));
    }
    if (lane == 0) {
      sTerm = __logf(g_all[row]) - __logf(p);
      cTerm = 1.f;
    }
  }

  __shared__ float bS[4], bC[4];
  if (lane == 0) { bS[w] = sTerm; bC[w] = cTerm; }
  __syncthreads();
  if (tid == 0) {
    atomicAdd(accS, (bS[0] + bS[1]) + (bS[2] + bS[3]));
    atomicAdd(accC, (bC[0] + bC[1]) + (bC[2] + bC[3]));
    __threadfence();
    const int old = atomicAdd(done, 1);
    if (old == nblocks - 1) {
      const float S = atomicAdd(accS, 0.f);   // atomic read (coherent)
      const float C = atomicAdd(accC, 0.f);
      out[0] = S / fmaxf(C, 1.f);
    }
  }
}

extern "C" void kernel_launch(void* const* d_in, const int* in_sizes, int n_in,
                              void* d_out, int out_size, void* d_ws, size_t ws_size,
                              hipStream_t stream) {
  const float* logits = (const float*)d_in[0];
  const float* labels = (const float*)d_in[1];
  const int*   pad    = (const int*)d_in[2];
  const int*   ad     = (const int*)d_in[3];

  char* ws = (char*)d_ws;
  unsigned char* qb = (unsigned char*)(ws);             // 2 MiB (fp8)
  unsigned char* kb = (unsigned char*)(ws + 2097152);   // 2 MiB (fp8)
  float* cb    = (float*)(ws + 4194304);                // 32 KiB
  float* gAll  = (float*)(ws + 4227072);                // 32 KiB
  int*   cnt   = (int*)  (ws + 4259840);                // 2 KiB (512 ints)
  float* accS  = (float*)(ws + 4261888);
  float* accC  = (float*)(ws + 4261892);
  int*   done  = (int*)  (ws + 4261896);
  int*   lists = (int*)  (ws + 4325376);                // 1 MiB (512*512 ints)
  float* out   = (float*)d_out;

  prep_kernel<<<4096, 256, 0, stream>>>(logits, labels, pad, qb, kb, cb, gAll,
                                        cnt, accS, accC, done);
  gemm_lse_kernel<<<dim3(64, 8), 256, 0, stream>>>(qb, kb, cb, ad, pad, gAll,
                                                   cnt, lists);
  pos_loss_kernel<<<2048, 256, 0, stream>>>(qb, kb, gAll, pad, ad, cnt, lists,
                                            accS, accC, done, out, 2048);
}

// Round 10
// 105.422 us; speedup vs baseline: 1.6537x; 1.6537x over previous
//
#include <hip/hip_runtime.h>
#include <hip/hip_bf16.h>
#include <hip/hip_fp8.h>
#include <math.h>

typedef float f32x4 __attribute__((ext_vector_type(4)));
typedef int   i32x4 __attribute__((ext_vector_type(4)));
typedef int   v8i   __attribute__((ext_vector_type(8)));

constexpr int Nn = 8192;   // B*S
constexpr int Dd = 256;    // feature dim (== bytes per fp8 row)
constexpr float LOG2E     = 1.4426950408889634f;
constexpr float SIM_SCALE = 20.0f * LOG2E;   // (1/tau)*log2(e), tau=0.05
constexpr float SIM_BIAS  = -20.0f * LOG2E;  // fixed max = 1/tau (|q.k|<=1)
constexpr int   SCALE1    = 0x7F7F7F7F;      // E8M0 127 = 2^0 in every byte
constexpr int   BCAP      = 512;             // bucket capacity (mean ~8)

// async global->LDS DMA, 16B/lane; LDS dst = wave-uniform base + lane*16.
typedef __attribute__((address_space(1))) const unsigned int gu32;
typedef __attribute__((address_space(3))) unsigned int lu32;
__device__ __forceinline__ void gload16(const unsigned char* g, unsigned char* l) {
  __builtin_amdgcn_global_load_lds((gu32*)(uintptr_t)g, (lu32*)(uintptr_t)l, 16, 0, 0);
}

#define VMCNT4() asm volatile("s_waitcnt vmcnt(4)" ::: "memory")
#define VMCNT0() asm volatile("s_waitcnt vmcnt(0)" ::: "memory")
#define LGKM0()  asm volatile("s_waitcnt lgkmcnt(0)" ::: "memory")
#define SCHEDB() __builtin_amdgcn_sched_barrier(0)
#define BAR()    __builtin_amdgcn_s_barrier()

__device__ __forceinline__ float fp8f(unsigned int b) {
  __hip_fp8_e4m3 v; v.__x = (unsigned char)(b & 0xffu); return (float)v;
}

// ---------------------------------------------------------------------------
// Kernel 1: L2-normalize rows -> fp8 e4m3; init cbias (SIM_BIAS pre-folded),
// g_all, bucket counts.  (R22-verified.)
// ---------------------------------------------------------------------------
__global__ __launch_bounds__(256) void prep_kernel(const float* __restrict__ logits,
                                                   const float* __restrict__ labels,
                                                   const int* __restrict__ pad,
                                                   unsigned char* __restrict__ qb,
                                                   unsigned char* __restrict__ kb,
                                                   float* __restrict__ cbias,
                                                   float* __restrict__ g_all,
                                                   int* __restrict__ cnt) {
  const int j = blockIdx.x * 256 + threadIdx.x;
  if (j < Nn) {
    cbias[j] = pad[j] ? SIM_BIAS : -1e30f;   // SIM_BIAS folded in (col term)
    g_all[j] = 0.0f;
  }
  if (j < BCAP) cnt[j] = 0;

  const int gw   = (blockIdx.x * 256 + threadIdx.x) >> 6;
  const int lane = threadIdx.x & 63;
  const float* src;
  unsigned char* dst;
  int row;
  if (gw < Nn) { src = logits; dst = qb; row = gw; }
  else         { src = labels; dst = kb; row = gw - Nn; }

  const float4 v = *reinterpret_cast<const float4*>(src + (size_t)row * Dd + lane * 4);
  float ss = v.x * v.x + v.y * v.y + v.z * v.z + v.w * v.w;
#pragma unroll
  for (int m = 32; m >= 1; m >>= 1) ss += __shfl_xor(ss, m);
  const float scale = 1.0f / fmaxf(sqrtf(ss), 1e-12f);

  const __hip_fp8_e4m3 e0(v.x * scale);
  const __hip_fp8_e4m3 e1(v.y * scale);
  const __hip_fp8_e4m3 e2(v.z * scale);
  const __hip_fp8_e4m3 e3(v.w * scale);
  const unsigned int packed = (unsigned int)e0.__x |
                              ((unsigned int)e1.__x << 8) |
                              ((unsigned int)e2.__x << 16) |
                              ((unsigned int)e3.__x << 24);
  reinterpret_cast<unsigned int*>(dst + (size_t)row * Dd)[lane] = packed;
}

// ---------------------------------------------------------------------------
// Kernel 2 (R22-verified, unchanged): R19 skeleton (LDS 3-slot B ring, counted
// vmcnt, A-hoist, atomics-at-retire) with the all-sum-only epilogue
// (fmaf+exp2+add per element) and the bucket fill on blockIdx.y==0.
// ---------------------------------------------------------------------------
__global__ __launch_bounds__(256, 2) void gemm_lse_kernel(const unsigned char* __restrict__ qb,
                                                          const unsigned char* __restrict__ kb,
                                                          const float* __restrict__ cbias,
                                                          const int* __restrict__ ad,
                                                          const int* __restrict__ pad,
                                                          float* __restrict__ g_all,
                                                          int* __restrict__ cnt,
                                                          int* __restrict__ lists) {
  __shared__ unsigned char smem[49152];
  // prologue: A.k0 [0,16K), A.k1 [16K,32K), B slot0 [32K,48K)
  // loop: B ring slot0=[32K,48K) slot1=[0,16K) slot2=[16K,32K), tile t -> t%3

  const int tid  = threadIdx.x;

  // ---- bucket fill (64 blocks x 256 thr >= 8192; readers run next kernel) --
  if (blockIdx.y == 0) {
    const int t = blockIdx.x * 256 + tid;
    if (t < Nn && pad[t]) {
      const int a = ad[t];
      const int slot = atomicAdd(&cnt[a], 1);
      if (slot < BCAP) lists[a * BCAP + slot] = t;
    }
  }

  const int lane = tid & 63;
  const int w    = tid >> 6;        // 0..3
  const int wrow  = (w >> 1) * 64;  // 0 or 64
  const int wcolL = (w & 1) * 64;   // 0 or 64 within the 128-col tile
  const int lq   = lane & 15;
  const int qd   = lane >> 4;
  const int rowBase = blockIdx.x * 128;
  const int colBase = blockIdx.y * 1024;   // 8 col-tiles of 128

  // staging constants (verified): wave w, iter i fills 8 LDS rows;
  // lane l -> row +(l>>3), logical 16B group (l&7)^(l>>3) (linear LDS dst).
  const int srl = lane >> 3;
  const int cg  = (lane & 7) ^ srl;
  const unsigned char* gA0 = qb + (size_t)(rowBase + w * 32 + srl) * Dd + cg * 16;
  const unsigned char* gB0 = kb + (size_t)(colBase + w * 32 + srl) * Dd + cg * 16;

  // ---- prologue: stage A (both K-halves) then B tile0 -> slot0 ----
#pragma unroll
  for (int kk = 0; kk < 2; ++kk)
#pragma unroll
    for (int i = 0; i < 4; ++i)
      gload16(gA0 + (size_t)i * 8 * Dd + kk * 128,
              &smem[kk * 16384 + (w * 32 + i * 8) * 128]);
#pragma unroll
  for (int i = 0; i < 4; ++i)
    gload16(gB0 + (size_t)i * 8 * Dd, &smem[32768 + (w * 32 + i * 8) * 128]);

  float apA[4][4];
#pragma unroll
  for (int mt = 0; mt < 4; ++mt)
#pragma unroll
    for (int r = 0; r < 4; ++r)
      apA[mt][r] = 0.f;

  VMCNT4();   // A's 8 loads (oldest) complete; tile0's 4 may remain
  BAR();

  // ---- one-time A fragment hoist (A LDS region dead afterwards) ----
  const int sl = lq & 7;                  // == r&7 for every fragment row
  const int s0 = ((qd * 2) ^ sl) << 4;
  const int s1 = ((qd * 2 + 1) ^ sl) << 4;

  v8i afReg[2][4];
#pragma unroll
  for (int kk = 0; kk < 2; ++kk) {
    const unsigned char* Ah = &smem[kk * 16384];
#pragma unroll
    for (int mt = 0; mt < 4; ++mt) {
      const int rb = (wrow + mt * 16 + lq) * 128;
      i32x4* ph_ = reinterpret_cast<i32x4*>(&afReg[kk][mt]);
      ph_[0] = *reinterpret_cast<const i32x4*>(&Ah[rb + s0]);
      ph_[1] = *reinterpret_cast<const i32x4*>(&Ah[rb + s1]);
    }
  }

  __syncthreads();  // full drain (once): hoist reads done in ALL waves before
                    // slots 1/2 overwrite the A region; tile0 DMA also done.

  {  // issue tile1 -> slot1 [0,16K)
    unsigned char* dB = &smem[0 + (w * 32) * 128];
    const unsigned char* g = gB0 + 128;  // ct=0, kk=1
#pragma unroll
    for (int i = 0; i < 4; ++i)
      gload16(g + (size_t)i * 8 * Dd, dB + i * 8 * 128);
  }

  const f32x4 CZ = (f32x4){0.f, 0.f, 0.f, 0.f};
  f32x4 c[4][4];
  float colB[4];

  for (int ct = 0; ct < 8; ++ct) {
    // slot bases for tiles 2ct, 2ct+1, 2ct+2, 2ct+3 (ring: tile t -> t%3)
    const int sA = (2 * ct) % 3;
    const unsigned bas0 = (sA == 0) ? 32768u : ((sA == 1) ? 0u : 16384u);
    const unsigned bas1 = (sA == 2) ? 32768u : ((sA == 0) ? 0u : 16384u);   // (2ct+1)%3
    const unsigned bas2 = (sA == 1) ? 32768u : ((sA == 2) ? 0u : 16384u);   // (2ct+2)%3
    const unsigned bas3 = bas0;                                             // (2ct+3)%3

    // ================= t = 2ct (kk=0): C-in = 0 =================
    {
      VMCNT4();   // tile 2ct (issued 2 barriers ago) complete; 2ct+1 in flight
      BAR();

      // col metadata first (so its vmcnt slot retires before the stage's)
#pragma unroll
      for (int nt = 0; nt < 4; ++nt)
        colB[nt] = cbias[colBase + ct * 128 + wcolL + nt * 16 + lq];

      if (ct < 7) {  // issue tile 2ct+2 -> bas2 (its old readers are done)
        unsigned char* dB = &smem[bas2 + (w * 32) * 128];
        const unsigned char* g = gB0 + (size_t)((ct + 1) * 128) * Dd;
#pragma unroll
        for (int i = 0; i < 4; ++i)
          gload16(g + (size_t)i * 8 * Dd, dB + i * 8 * 128);
      }

      const unsigned char* Bh = &smem[bas0];
#pragma unroll
      for (int nt = 0; nt < 4; ++nt) {
        const int rb = (wcolL + nt * 16 + lq) * 128;
        v8i bf;
        i32x4* pb = reinterpret_cast<i32x4*>(&bf);
        pb[0] = *reinterpret_cast<const i32x4*>(&Bh[rb + s0]);
        pb[1] = *reinterpret_cast<const i32x4*>(&Bh[rb + s1]);
#pragma unroll
        for (int mt = 0; mt < 4; ++mt)
          c[mt][nt] = __builtin_amdgcn_mfma_scale_f32_16x16x128_f8f6f4(
              afReg[0][mt], bf, CZ, 0, 0, 0, SCALE1, 0, SCALE1);
      }
      LGKM0();   // pin this phase's ds_reads inside the phase (rule #18)
      SCHEDB();
    }

    // ================= t = 2ct+1 (kk=1): accumulate + epilogue =================
    {
      if (ct < 7) { VMCNT4(); } else { VMCNT0(); }  // tile 2ct+1 complete
      BAR();

      if (ct < 7) {  // issue tile 2ct+3 -> bas3
        unsigned char* dB = &smem[bas3 + (w * 32) * 128];
        const unsigned char* g = gB0 + (size_t)((ct + 1) * 128) * Dd + 128;
#pragma unroll
        for (int i = 0; i < 4; ++i)
          gload16(g + (size_t)i * 8 * Dd, dB + i * 8 * 128);
      }

      const unsigned char* Bh = &smem[bas1];
#pragma unroll
      for (int nt = 0; nt < 4; ++nt) {
        const int rb = (wcolL + nt * 16 + lq) * 128;
        v8i bf;
        i32x4* pb = reinterpret_cast<i32x4*>(&bf);
        pb[0] = *reinterpret_cast<const i32x4*>(&Bh[rb + s0]);
        pb[1] = *reinterpret_cast<const i32x4*>(&Bh[rb + s1]);
#pragma unroll
        for (int mt = 0; mt < 4; ++mt)
          c[mt][nt] = __builtin_amdgcn_mfma_scale_f32_16x16x128_f8f6f4(
              afReg[1][mt], bf, c[mt][nt], 0, 0, 0, SCALE1, 0, SCALE1);
      }
      LGKM0();
      SCHEDB();

      // ---- epilogue: all-sum only (fmaf + exp2 + add per element) ----
#pragma unroll
      for (int mt = 0; mt < 4; ++mt) {
#pragma unroll
        for (int r = 0; r < 4; ++r) {
          float a = 0.f;
#pragma unroll
          for (int nt = 0; nt < 4; ++nt)
            a += __builtin_amdgcn_exp2f(fmaf(c[mt][nt][r], SIM_SCALE, colB[nt]));
          apA[mt][r] += a;
        }
      }
    }
  }

  // ---- final reduction: shfl-tree over the 16 lq lanes, then one atomic ----
#pragma unroll
  for (int mt = 0; mt < 4; ++mt) {
#pragma unroll
    for (int r = 0; r < 4; ++r) {
      float a = apA[mt][r];
#pragma unroll
      for (int m = 1; m < 16; m <<= 1)
        a += __shfl_xor(a, m);
      if (lq == 0) {
        const int row = rowBase + wrow + mt * 16 + qd * 4 + r;
        atomicAdd(&g_all[row], a);
      }
    }
  }
}

// ---------------------------------------------------------------------------
// Kernel 3 (R23): sparse pos-sum, CONTENTION-FREE.  One wave per row:
// p = sum over bucket[ad_row] of exp2(q.k * SIM_SCALE + SIM_BIAS), then a
// single plain store g_pos[row] = p.  No atomics, no fences (R22's 85us was
// 2048 blocks serializing same-address device atomics + threadfence).
// ---------------------------------------------------------------------------
__global__ __launch_bounds__(256) void pos_kernel(const unsigned char* __restrict__ qb,
                                                  const unsigned char* __restrict__ kb,
                                                  const int* __restrict__ pad,
                                                  const int* __restrict__ ad,
                                                  const int* __restrict__ cnt,
                                                  const int* __restrict__ lists,
                                                  float* __restrict__ g_pos) {
  const int tid  = threadIdx.x;
  const int lane = tid & 63;
  const int w    = tid >> 6;
  const int row  = blockIdx.x * 4 + w;

  if (!pad[row]) return;   // reduce checks pad; g_pos[row] never read

  const unsigned int qw =
      reinterpret_cast<const unsigned int*>(qb + (size_t)row * Dd)[lane];
  const float q0 = fp8f(qw), q1 = fp8f(qw >> 8),
              q2 = fp8f(qw >> 16), q3 = fp8f(qw >> 24);
  const int a = ad[row];
  int m = cnt[a];
  if (m > BCAP) m = BCAP;          // impossible for this input; safety
  const int* lst = lists + a * BCAP;

  float p = 0.f;
  // 2-deep prefetch over the bucket (m >= 1: row itself is in its bucket)
  unsigned int kw =
      reinterpret_cast<const unsigned int*>(kb + (size_t)lst[0] * Dd)[lane];
  for (int s = 0; s < m; ++s) {
    const unsigned int kwc = kw;
    if (s + 1 < m)
      kw = reinterpret_cast<const unsigned int*>(kb + (size_t)lst[s + 1] * Dd)[lane];
    float d = q0 * fp8f(kwc);
    d = fmaf(q1, fp8f(kwc >> 8), d);
    d = fmaf(q2, fp8f(kwc >> 16), d);
    d = fmaf(q3, fp8f(kwc >> 24), d);
#pragma unroll
    for (int mm = 32; mm >= 1; mm >>= 1) d += __shfl_xor(d, mm);
    p += __builtin_amdgcn_exp2f(fmaf(d, SIM_SCALE, SIM_BIAS));
  }
  if (lane == 0) g_pos[row] = p;
}

// ---------------------------------------------------------------------------
// Kernel 4: loss = mean over valid rows of log(g_all) - log(g_pos).
// (R13-verified single-block reduce, ~2us.)
// ---------------------------------------------------------------------------
__global__ __launch_bounds__(1024) void reduce_kernel(const float* __restrict__ g_all,
                                                      const float* __restrict__ g_pos,
                                                      const int* __restrict__ pad,
                                                      float* __restrict__ out) {
  __shared__ float sS[16], sC[16];
  const int t = threadIdx.x;
  float s = 0.f, c = 0.f;
  const float4* ga4 = (const float4*)g_all;
  const float4* gp4 = (const float4*)g_pos;
  const int4*   pd4 = (const int4*)pad;
  for (int i = t; i < Nn / 4; i += 1024) {
    const float4 ga = ga4[i];
    const float4 gp = gp4[i];
    const int4   pd = pd4[i];
    if (pd.x) { s += __logf(ga.x) - __logf(gp.x); c += 1.f; }
    if (pd.y) { s += __logf(ga.y) - __logf(gp.y); c += 1.f; }
    if (pd.z) { s += __logf(ga.z) - __logf(gp.z); c += 1.f; }
    if (pd.w) { s += __logf(ga.w) - __logf(gp.w); c += 1.f; }
  }
#pragma unroll
  for (int m = 32; m >= 1; m >>= 1) {
    s += __shfl_xor(s, m);
    c += __shfl_xor(c, m);
  }
  if ((t & 63) == 0) { sS[t >> 6] = s; sC[t >> 6] = c; }
  __syncthreads();
  if (t == 0) {
    float S = 0.f, C = 0.f;
#pragma unroll
    for (int i = 0; i < 16; ++i) { S += sS[i]; C += sC[i]; }
    out[0] = S / fmaxf(C, 1.0f);
  }
}

extern "C" void kernel_launch(void* const* d_in, const int* in_sizes, int n_in,
                              void* d_out, int out_size, void* d_ws, size_t ws_size,
                              hipStream_t stream) {
  const float* logits = (const float*)d_in[0];
  const float* labels = (const float*)d_in[1];
  const int*   pad    = (const int*)d_in[2];
  const int*   ad     = (const int*)d_in[3];

  char* ws = (char*)d_ws;
  unsigned char* qb = (unsigned char*)(ws);             // 2 MiB (fp8)
  unsigned char* kb = (unsigned char*)(ws + 2097152);   // 2 MiB (fp8)
  float* cb    = (float*)(ws + 4194304);                // 32 KiB
  float* gAll  = (float*)(ws + 4227072);                // 32 KiB
  float* gPos  = (float*)(ws + 4259840);                // 32 KiB
  int*   cnt   = (int*)  (ws + 4292608);                // 2 KiB (512 ints)
  int*   lists = (int*)  (ws + 4325376);                // 1 MiB (512*512 ints)
  float* out   = (float*)d_out;

  prep_kernel<<<4096, 256, 0, stream>>>(logits, labels, pad, qb, kb, cb, gAll, cnt);
  gemm_lse_kernel<<<dim3(64, 8), 256, 0, stream>>>(qb, kb, cb, ad, pad, gAll,
                                                   cnt, lists);
  pos_kernel<<<2048, 256, 0, stream>>>(qb, kb, pad, ad, cnt, lists, gPos);
  reduce_kernel<<<1, 1024, 0, stream>>>(gAll, gPos, pad, out);
}